// Round 2
// baseline (632.805 us; speedup 1.0000x reference)
//
#include <hip/hip_runtime.h>
#include <hip/hip_bf16.h>

// Problem constants
constexpr int BN = 8, HH = 512, WW = 512;
constexpr int PIX = HH * WW;              // 262144
constexpr float EPSF = 1e-4f;

__device__ __forceinline__ float b2f(__hip_bfloat16 x) { return __bfloat162float(x); }
__device__ __forceinline__ __hip_bfloat16 f2b(float x) { return __float2bfloat16(x); }

// ---- workspace layout ----
// wsf[0..7]    : sums (one per image)
// wsf[16..311] : ehat (8*37)
// wsf[512..807]: chat (8*37)
// byte 65536   : big region — h1 (bf16, 67 MB) | h2 (bf16, 67 MB)
//                after conv2, h1 region is reused for xg (fp32, 25 MB) + tpl (fp32 4 planes, 33.5 MB)
constexpr size_t BIG_F = 16384;                           // float offset (byte 65536)
constexpr size_t H1_BYTES = (size_t)BN * 16 * PIX * 2;    // 67,108,864
constexpr size_t H2_BYTE_OFF = 65536 + H1_BYTES;
constexpr size_t WS_NEEDED = H2_BYTE_OFF + H1_BYTES;      // 134,283,264 (confirmed to fit)

// ---------------- conv1: batch(fp32 NCHW,3ch) -> h1(bf16,16ch), silu ----------------
__global__ __launch_bounds__(256) void conv1_kernel(const float* __restrict__ batch,
                                                    const float* __restrict__ w1,
                                                    const float* __restrict__ b1,
                                                    __hip_bfloat16* __restrict__ h1) {
    int w = blockIdx.x * 64 + threadIdx.x;
    int h = blockIdx.y * 4 + threadIdx.y;
    int b = blockIdx.z;
    float v[27];
#pragma unroll
    for (int ic = 0; ic < 3; ic++) {
        const float* p = batch + (size_t)(b * 3 + ic) * PIX;
#pragma unroll
        for (int kh = 0; kh < 3; kh++) {
            int hh = h + kh - 1;
#pragma unroll
            for (int kw = 0; kw < 3; kw++) {
                int ww = w + kw - 1;
                float x = 0.f;
                if (hh >= 0 && hh < HH && ww >= 0 && ww < WW) x = p[hh * WW + ww];
                v[ic * 9 + kh * 3 + kw] = x;
            }
        }
    }
#pragma unroll
    for (int oc = 0; oc < 16; oc++) {
        float a = b1[oc];
#pragma unroll
        for (int j = 0; j < 27; j++) a += v[j] * w1[oc * 27 + j];   // uniform idx -> scalar loads
        a = a / (1.f + __expf(-a));   // silu
        h1[(size_t)(b * 16 + oc) * PIX + h * WW + w] = f2b(a);
    }
}

// ---------------- conv2: h1 -> h2 (16->16), silu ----------------
__global__ __launch_bounds__(256) void conv2_kernel(const __hip_bfloat16* __restrict__ h1,
                                                    const float* __restrict__ w2,
                                                    const float* __restrict__ b2,
                                                    __hip_bfloat16* __restrict__ h2) {
    int w = blockIdx.x * 64 + threadIdx.x;
    int h = blockIdx.y * 4 + threadIdx.y;
    int b = blockIdx.z;
    float acc[16];
#pragma unroll
    for (int oc = 0; oc < 16; oc++) acc[oc] = b2[oc];
    for (int ic = 0; ic < 16; ic++) {
        const __hip_bfloat16* p = h1 + (size_t)(b * 16 + ic) * PIX;
        float v[9];
#pragma unroll
        for (int kh = 0; kh < 3; kh++) {
            int hh = h + kh - 1;
#pragma unroll
            for (int kw = 0; kw < 3; kw++) {
                int ww = w + kw - 1;
                float x = 0.f;
                if (hh >= 0 && hh < HH && ww >= 0 && ww < WW) x = b2f(p[hh * WW + ww]);
                v[kh * 3 + kw] = x;
            }
        }
        const float* Wp = w2 + ic * 9;      // oc*144+k below is wave-uniform -> scalar loads
#pragma unroll
        for (int oc = 0; oc < 16; oc++) {
#pragma unroll
            for (int k = 0; k < 9; k++) acc[oc] += v[k] * Wp[oc * 144 + k];
        }
    }
#pragma unroll
    for (int oc = 0; oc < 16; oc++) {
        float a = acc[oc];
        a = a / (1.f + __expf(-a));
        h2[(size_t)(b * 16 + oc) * PIX + h * WW + w] = f2b(a);
    }
}

// ---------------- conv3 + mean-reduce: h2 -> atomic sums[b] ----------------
__global__ __launch_bounds__(256) void conv3_kernel(const __hip_bfloat16* __restrict__ h2,
                                                    const float* __restrict__ w3,
                                                    const float* __restrict__ b3,
                                                    float* __restrict__ sums) {
    int w = blockIdx.x * 64 + threadIdx.x;
    int h = blockIdx.y * 4 + threadIdx.y;
    int b = blockIdx.z;
    float a = b3[0];
    for (int ic = 0; ic < 16; ic++) {
        const __hip_bfloat16* p = h2 + (size_t)(b * 16 + ic) * PIX;
#pragma unroll
        for (int kh = 0; kh < 3; kh++) {
            int hh = h + kh - 1;
#pragma unroll
            for (int kw = 0; kw < 3; kw++) {
                int ww = w + kw - 1;
                float x = 0.f;
                if (hh >= 0 && hh < HH && ww >= 0 && ww < WW) x = b2f(p[hh * WW + ww]);
                a += x * w3[ic * 9 + kh * 3 + kw];
            }
        }
    }
    __shared__ float red[256];
    int tid = threadIdx.y * 64 + threadIdx.x;
    red[tid] = a;
    __syncthreads();
    for (int s = 128; s > 0; s >>= 1) {
        if (tid < s) red[tid] += red[tid + s];
        __syncthreads();
    }
    if (tid == 0) atomicAdd(&sums[b], red[0]);
}

// ---------------- per-image separable filter taps ----------------
__global__ void filter_kernel(const float* __restrict__ sums, float* __restrict__ ehat,
                              float* __restrict__ chat) {
    int b = blockIdx.x; int t = threadIdx.x;
    float scale = sums[b] * (1.f / (float)PIX);
    scale = fminf(2.5f, fmaxf(-2.5f, scale));
    float sd = exp2f(scale);
    float fs = ceilf(3.f * sd + 0.5f);
    __shared__ float se[64], sc[64];
    __shared__ float Se, Sc;
    float e = 0.f, c = 0.f;
    if (t < 37) {
        float x = (float)(t - 18);
        if (fabsf(x) <= fs) {
            float q = x / sd;
            e = __expf(-0.5f * q * q);
            c = -x / (sd * sd * sd * 6.28318530717958647692f) * e;
        }
    }
    se[t] = e; sc[t] = fabsf(c);
    __syncthreads();
    if (t == 0) {
        float a = 0.f, d = 0.f;
        for (int i = 0; i < 37; i++) { a += se[i]; d += sc[i]; }
        Se = a; Sc = d;
    }
    __syncthreads();
    if (t < 37) {
        ehat[b * 37 + t] = e / Se;
        chat[b * 37 + t] = c / Sc;
    }
}

// ---------------- xg = gcm*batch (fp32) + RGB_order -> out ch2..4 ----------------
__global__ __launch_bounds__(256) void xgrgb_kernel(const float* __restrict__ batch,
                                                    const float* __restrict__ gcm,
                                                    float* __restrict__ xg,
                                                    float* __restrict__ out) {
    int w = blockIdx.x * 64 + threadIdx.x;
    int h = blockIdx.y * 4 + threadIdx.y;
    int b = blockIdx.z;
    int p = h * WW + w;
    float v0 = batch[(size_t)(b * 3 + 0) * PIX + p];
    float v1 = batch[(size_t)(b * 3 + 1) * PIX + p];
    float v2 = batch[(size_t)(b * 3 + 2) * PIX + p];
#pragma unroll
    for (int i = 0; i < 3; i++)
        xg[(size_t)(b * 3 + i) * PIX + p] = gcm[i * 3] * v0 + gcm[i * 3 + 1] * v1 + gcm[i * 3 + 2] * v2;
    int mx  = (v0 >= v1 && v0 >= v2) ? 0 : ((v1 >= v2) ? 1 : 2);   // first max
    int mx2 = (v2 >= v1 && v2 >= v0) ? 2 : ((v1 >= v0) ? 1 : 0);   // last max
    int mn  = (v0 <= v1 && v0 <= v2) ? 0 : ((v1 <= v2) ? 1 : 2);   // first min
    int mn2 = (v2 <= v1 && v2 <= v0) ? 2 : ((v1 <= v0) ? 1 : 0);   // last min
#pragma unroll
    for (int c = 0; c < 3; c++) {
        float r = 0.5f * ((float)(c == mx) + (float)(c == mx2))
                - 0.5f * ((float)(c == mn) + (float)(c == mn2));
        out[(size_t)(b * 6 + 2 + c) * PIX + p] = r;
    }
}

// ---------------- horizontal separable pass: xg -> t0..t3 ----------------
// t0=He(xg0), t1=He(xg1), t2=He(xg2), t3=Hc(xg0)   (H* = 1-D correlation along W)
__global__ __launch_bounds__(256) void horiz_kernel(const float* __restrict__ xg,
                                                    const float* __restrict__ ehat,
                                                    const float* __restrict__ chat,
                                                    float* __restrict__ t) {
    __shared__ float L[3][296];
    int tid = threadIdx.x;
    int w0 = blockIdx.x * 256;
    int h = blockIdx.y;
    int b = blockIdx.z;
    for (int i = tid; i < 3 * 292; i += 256) {
        int c = i / 292, j = i - c * 292;
        int gw = w0 - 18 + j;
        float x = 0.f;
        if (gw >= 0 && gw < WW) x = xg[(size_t)(b * 3 + c) * PIX + h * WW + gw];
        L[c][j] = x;
    }
    __syncthreads();
    const float* eh = ehat + b * 37; const float* ch = chat + b * 37;
    float s0e = 0.f, s0c = 0.f, s1e = 0.f, s2e = 0.f;
    for (int k = 0; k < 37; k++) {
        float ce = eh[k], cc = ch[k];           // wave-uniform -> scalar loads
        float a0 = L[0][tid + k], a1 = L[1][tid + k], a2 = L[2][tid + k];
        s0e += ce * a0; s0c += cc * a0; s1e += ce * a1; s2e += ce * a2;
    }
    int w = w0 + tid;
    size_t p = (size_t)b * PIX + h * WW + w;
    const size_t PL = (size_t)BN * PIX;
    t[0 * PL + p] = s0e;
    t[1 * PL + p] = s1e;
    t[2 * PL + p] = s2e;
    t[3 * PL + p] = s0c;
}

// ---------------- vertical pass + final math -> out ch0,1,5 ----------------
// E=Ve(t0), Ex=Vc(t0), Ey=Ve(t3), El=Ve(t1), Ell=Ve(t2)   (V* = 1-D correlation along H)
__global__ __launch_bounds__(256) void vert_kernel(const float* __restrict__ t,
                                                   const float* __restrict__ ehat,
                                                   const float* __restrict__ chat,
                                                   float* __restrict__ out) {
    int w = blockIdx.x * 64 + threadIdx.x;
    int h = blockIdx.y * 4 + threadIdx.y;
    int b = blockIdx.z;
    const float* eh = ehat + b * 37; const float* ch = chat + b * 37;
    const size_t PL = (size_t)BN * PIX;
    const float* t0 = t + 0 * PL + (size_t)b * PIX;
    const float* t1 = t + 1 * PL + (size_t)b * PIX;
    const float* t2 = t + 2 * PL + (size_t)b * PIX;
    const float* t3 = t + 3 * PL + (size_t)b * PIX;
    float E = 0.f, Ex = 0.f, Ey = 0.f, El = 0.f, Ell = 0.f;
    for (int k = 0; k < 37; k++) {
        int hh = h - 18 + k;
        if (hh < 0 || hh >= HH) continue;
        float ce = eh[k], cc = ch[k];
        int idx = hh * WW + w;
        float a0 = t0[idx], a1 = t1[idx], a2 = t2[idx], a3 = t3[idx];
        E += ce * a0; Ex += cc * a0; Ey += ce * a3; El += ce * a1; Ell += ce * a2;
    }
    float Hf = atanf(El / (Ell + EPSF));
    float S = logf((El * El + Ell * Ell) / (E * E + EPSF) + EPSF);
    float rx = Ex / (E + EPSF), ry = Ey / (E + EPSF);
    float Wv = atanf(rx * rx + ry * ry);
    size_t base = (size_t)(b * 6) * PIX + h * WW + w;
    out[base] = Hf;
    out[base + PIX] = S;
    out[base + 5 * (size_t)PIX] = Wv;
}

extern "C" void kernel_launch(void* const* d_in, const int* in_sizes, int n_in,
                              void* d_out, int out_size, void* d_ws, size_t ws_size,
                              hipStream_t stream) {
    const float* batch = (const float*)d_in[0];
    const float* gcm   = (const float*)d_in[1];
    const float* w1    = (const float*)d_in[2];
    const float* b1    = (const float*)d_in[3];
    const float* w2    = (const float*)d_in[4];
    const float* b2    = (const float*)d_in[5];
    const float* w3    = (const float*)d_in[6];
    const float* b3    = (const float*)d_in[7];
    float* out = (float*)d_out;

    if (ws_size < WS_NEEDED) return;   // fail loudly (wrong output), never OOB

    float* wsf  = (float*)d_ws;
    float* sums = wsf;           // 8 floats
    float* ehat = wsf + 16;      // 8*37
    float* chat = wsf + 512;     // 8*37
    __hip_bfloat16* h1 = (__hip_bfloat16*)(wsf + BIG_F);
    __hip_bfloat16* h2 = (__hip_bfloat16*)((char*)d_ws + H2_BYTE_OFF);
    float* xg  = wsf + BIG_F;                        // aliases h1 (dead after conv2)
    float* tpl = wsf + BIG_F + (size_t)BN * 3 * PIX; // 4 planes, still inside h1 region

    hipMemsetAsync(sums, 0, 8 * sizeof(float), stream);

    dim3 blk(64, 4), grd(WW / 64, HH / 4, BN);
    conv1_kernel<<<grd, blk, 0, stream>>>(batch, w1, b1, h1);
    conv2_kernel<<<grd, blk, 0, stream>>>(h1, w2, b2, h2);
    conv3_kernel<<<grd, blk, 0, stream>>>(h2, w3, b3, sums);
    filter_kernel<<<dim3(8), dim3(64), 0, stream>>>(sums, ehat, chat);
    xgrgb_kernel<<<grd, blk, 0, stream>>>(batch, gcm, xg, out);      // xg aliases h1 (now dead)
    horiz_kernel<<<dim3(WW / 256, HH, BN), dim3(256), 0, stream>>>(xg, ehat, chat, tpl);
    vert_kernel<<<grd, blk, 0, stream>>>(tpl, ehat, chat, out);
}